// Round 12
// baseline (342.388 us; speedup 1.0000x reference)
//
#include <hip/hip_runtime.h>

typedef unsigned short ushort_t;
typedef __attribute__((ext_vector_type(8))) short bf16x8;    // 8 bf16 = 4 VGPRs
typedef __attribute__((ext_vector_type(16))) float f32x16;   // 32x32 MFMA acc

#define MAXN 8192
#define CAND_CAP 2048

// ---- zero-prefill d_out (safety) ----
__global__ void prefill_kernel(float* __restrict__ out, int n) {
    for (int i = blockIdx.x * 256 + threadIdx.x; i < n; i += gridDim.x * 256)
        out[i] = 0.0f;
}

// ---- f32 -> bf16 cast (RNE), 8/thread ----
__global__ __launch_bounds__(256) void cast_bf16_kernel(
    const float* __restrict__ in, ushort_t* __restrict__ out, int n)
{
    int i = (blockIdx.x * 256 + threadIdx.x) * 8;
    if (i >= n) return;
    ushort_t o[8];
#pragma unroll
    for (int q = 0; q < 8; ++q) {
        unsigned u = __float_as_uint(in[i + q]);
        o[q] = (ushort_t)((u + 0x7FFFu + ((u >> 16) & 1u)) >> 16);
    }
    *(ushort4*)(out + i)     = make_ushort4(o[0], o[1], o[2], o[3]);
    *(ushort4*)(out + i + 4) = make_ushort4(o[4], o[5], o[6], o[7]);
}

// async global->LDS, 16B per lane; lds dest = wave-uniform base + lane*16
__device__ __forceinline__ void gload_lds16(const ushort_t* g, void* lds) {
    __builtin_amdgcn_global_load_lds(
        (const __attribute__((address_space(1))) unsigned int*)g,
        (__attribute__((address_space(3))) unsigned int*)lds, 16, 0, 0);
}

// ---- bf16 MFMA NT GEMM: C[i][j] = bf16(sum_k A[i][k]*B[j][k] (+bias[j])) ----
// 128x128 block tile, BK=64, 4 waves 2x2; wave tile 64x64 = 2x2 of 32x32x16.
// ~124 unified VGPRs, __launch_bounds__(256,4) -> 4 blocks/CU.
// tri=1: PACKED triangular grid — blockIdx.x is a flat index over live tiles
// only (round-11 post-mortem: 49% of the 2D grid was dead blocks). Decode:
// row-block b has (tbase + b + 1) column tiles; scalar loop finds (by,bx).
// LDS 16B-slot swizzle: slot(m,kq) = m*8 + (kq ^ (m&7)).
// C stored bf16 (ushort), leading dim ldc, LOCAL row indexing.
__global__ __launch_bounds__(256, 4) void gemm_bf16_nt(
    const ushort_t* __restrict__ A, const ushort_t* __restrict__ B,
    const float* __restrict__ bias, ushort_t* __restrict__ C,
    int K, int ldc, int tbase, int tri)
{
    int bx, by;
    if (tri) {
        int f = blockIdx.x;
        int b = 0, off = 0;
        while (off + tbase + b + 1 <= f) { off += tbase + b + 1; ++b; }
        by = b; bx = f - off;
    } else {
        bx = blockIdx.x; by = blockIdx.y;
    }
    const int j0 = bx * 128;

    __shared__ __align__(16) ushort_t sA[128 * 64];
    __shared__ __align__(16) ushort_t sB[128 * 64];

    const int tid   = threadIdx.x;
    const int lane  = tid & 63;
    const int w     = tid >> 6;
    const int wr    = (w >> 1) * 64;    // wave row offset (0/64)
    const int wc    = (w & 1) * 64;     // wave col offset (0/64)
    const int l31   = lane & 31;
    const int khalf = lane >> 5;

    const ushort_t* Ab = A + (size_t)by * 128 * K;
    const ushort_t* Bb = B + (size_t)bx * 128 * K;

    f32x16 acc[2][2];
#pragma unroll
    for (int r = 0; r < 2; ++r)
#pragma unroll
        for (int c = 0; c < 2; ++c)
#pragma unroll
            for (int e = 0; e < 16; ++e) acc[r][c][e] = 0.0f;

    for (int k0 = 0; k0 < K; k0 += 64) {
        // Stage A,B (128x64 each = 1024 16B slots each): 4 gloads/thread/array.
#pragma unroll
        for (int qq = 0; qq < 4; ++qq) {
            int id = tid + qq * 256;           // 0..1023
            int m  = id >> 3;
            int kc = ((id & 7) ^ (m & 7)) * 8;
            unsigned lb = (unsigned)(((tid & ~63) + qq * 256) * 16);
            gload_lds16(Ab + (size_t)m * K + k0 + kc, (char*)sA + lb);
            gload_lds16(Bb + (size_t)m * K + k0 + kc, (char*)sB + lb);
        }
        __syncthreads();

#pragma unroll
        for (int h = 0; h < 4; ++h) {          // four K=16 steps per K=64
            const int kq = h * 2 + khalf;
            bf16x8 fa[2], fb[2];
#pragma unroll
            for (int r = 0; r < 2; ++r) {
                int m = wr + r * 32 + l31;
                fa[r] = *(const bf16x8*)&sA[(m * 8 + (kq ^ (m & 7))) * 8];
            }
#pragma unroll
            for (int c = 0; c < 2; ++c) {
                int m = wc + c * 32 + l31;
                fb[c] = *(const bf16x8*)&sB[(m * 8 + (kq ^ (m & 7))) * 8];
            }
#pragma unroll
            for (int r = 0; r < 2; ++r)
#pragma unroll
                for (int c = 0; c < 2; ++c)
                    acc[r][c] = __builtin_amdgcn_mfma_f32_32x32x16_bf16(
                        fa[r], fb[c], acc[r][c], 0, 0, 0);
        }
        __syncthreads();
    }

    // Epilogue. 32x32 C/D layout (m74/m101): col = lane&31,
    // row = (reg&3) + 8*(reg>>2) + 4*(lane>>5). Store bf16 RNE.
#pragma unroll
    for (int r = 0; r < 2; ++r) {
#pragma unroll
        for (int c = 0; c < 2; ++c) {
            int colg = j0 + wc + c * 32 + l31;
            float bv = bias ? bias[colg] : 0.0f;
#pragma unroll
            for (int reg = 0; reg < 16; ++reg) {
                int rowl = (reg & 3) + 8 * (reg >> 2) + 4 * khalf;
                int row = by * 128 + wr + r * 32 + rowl;   // local row
                float v = acc[r][c][reg] + bv;
                unsigned u = __float_as_uint(v);
                C[(size_t)row * ldc + colg] =
                    (ushort_t)((u + 0x7FFFu + ((u >> 16) & 1u)) >> 16);
            }
        }
    }
}

// ---- fully-guarded naive fp32 NT GEMM -> f32 C (fallback only) ----
__global__ __launch_bounds__(256) void gemm_nt_naive(
    const float* __restrict__ A, const float* __restrict__ B,
    const float* __restrict__ bias, float* __restrict__ C,
    int K, int ldc, int rows, int cols)
{
    int j = blockIdx.x * 16 + (threadIdx.x & 15);
    int i = blockIdx.y * 16 + (threadIdx.x >> 4);
    if (i >= rows || j >= cols) return;
    float acc = bias ? bias[j] : 0.0f;
    const float* Ar = A + (size_t)i * K;
    const float* Br = B + (size_t)j * K;
    for (int k = 0; k < K; ++k) acc = fmaf(Ar[k], Br[k], acc);
    C[(size_t)i * ldc + j] = acc;
}

// ---- f32 -> bf16 strip cast (fallback) ----
__global__ __launch_bounds__(256) void cast_bf16_n_kernel(
    const float* __restrict__ in, ushort_t* __restrict__ out, size_t n)
{
    size_t i = (size_t)blockIdx.x * 256 + threadIdx.x;
    for (; i < n; i += (size_t)gridDim.x * 256) {
        unsigned u = __float_as_uint(in[i]);
        out[i] = (ushort_t)((u + 0x7FFFu + ((u >> 16) & 1u)) >> 16);
    }
}

// ---- threshold-pruned top-k per row on bf16 scores ----
__device__ __forceinline__ unsigned mono16(unsigned b) {
    return (b & 0x8000u) ? (~b & 0xFFFFu) : (b | 0x8000u);
}
__device__ __forceinline__ float inv_mono16(unsigned m) {
    unsigned b = (m & 0x8000u) ? (m & 0x7FFFu) : (~m & 0xFFFFu);
    return __uint_as_float(b << 16);
}
__device__ __forceinline__ float scrub(float v) {
    unsigned u = __float_as_uint(v);
    if (((u >> 23) & 0xFFu) == 0xFFu) return -1.0e30f;
    if (v < -1.0e37f) return -1.0e30f;
    return v;
}

// One block per row i = row_offset + blockIdx.x; S rows bf16, width N.
// Thread t owns j in [t*32, t*32+32). Round-12 redesign (round-11 PM: the
// full histogram was ~67M serialized LDS atomics): 
//  1. per-thread register max over its 32 values (no atomics),
//  2. radix-select the k-th largest of the 256 thread-maxima (256 atomics)
//     -> threshold L. Guarantee: >=k threads have max >= L, each contributes
//     >=1 value >= L => count_row(>=L) >= k => top-k all >= L.
//  3. compact values >= L (~k..3k candidates typically) and rank-by-count.
// Small rows: fewer than k nonzero maxima -> L=0 -> all valid compacted;
// nval <= 1568 in that case, < CAND_CAP. Key = (mono16<<13)|(8191-j):
// unique, max = max score, ties -> smaller j (JAX order).
__global__ __launch_bounds__(256) void topk_kernel(
    const ushort_t* __restrict__ S, int N, int row_offset, int k_out,
    float* __restrict__ out_s, float* __restrict__ out_i)
{
    const int i = row_offset + blockIdx.x;
    const ushort_t* row = S + (size_t)blockIdx.x * N;
    const int t = threadIdx.x;
    const int lane = t & 63;
    const int w = t >> 6;
    const int nval = (i < N) ? i : N;

    __shared__ unsigned hist4[4][257];
    __shared__ unsigned cand[CAND_CAP];
    __shared__ unsigned cand_cnt;
    __shared__ unsigned sT1, sAbove1, sT2;

    unsigned m16[32];
    unsigned tmax = 0;
    const int jbase = t * 32;
#pragma unroll
    for (int q = 0; q < 4; ++q) {
        int jb = jbase + q * 8;
        if (jb < nval) {
            ushort_t vv[8];
            if (jb + 8 <= N) {
                *(uint4*)vv = *(const uint4*)(row + jb);
            } else {
#pragma unroll
                for (int e = 0; e < 8; ++e) vv[e] = (jb + e < N) ? row[jb + e] : 0;
            }
#pragma unroll
            for (int e = 0; e < 8; ++e) {
                unsigned m = (jb + e < nval) ? mono16(vv[e]) : 0u;
                m16[q * 8 + e] = m;
                if (m > tmax) tmax = m;
            }
        } else {
#pragma unroll
            for (int e = 0; e < 8; ++e) m16[q * 8 + e] = 0u;
        }
    }

    if (t == 0) { sT1 = 0; sAbove1 = 0; sT2 = 0; cand_cnt = 0; }
#pragma unroll
    for (int q = 0; q < 4; ++q) hist4[q][t] = 0;
    __syncthreads();

    // Pass 1: histogram of thread-maxima top bytes (ONE atomic per thread)
    if (tmax) atomicAdd(&hist4[w][tmax >> 8], 1u);
    __syncthreads();
    if (w == 0) {
        int base = lane * 4;
        unsigned h[4];
#pragma unroll
        for (int r = 0; r < 4; ++r)
            h[r] = hist4[0][base + r] + hist4[1][base + r] +
                   hist4[2][base + r] + hist4[3][base + r];
        unsigned lsum = h[0] + h[1] + h[2] + h[3];
        unsigned suf = lsum;
#pragma unroll
        for (int off = 1; off < 64; off <<= 1) {
            unsigned o = __shfl_down(suf, off, 64);
            suf += (lane + off < 64) ? o : 0u;
        }
        unsigned Sr[5];
        Sr[4] = suf - lsum;
#pragma unroll
        for (int r = 3; r >= 0; --r) Sr[r] = Sr[r + 1] + h[r];
#pragma unroll
        for (int r = 0; r < 4; ++r)
            if (Sr[r] >= (unsigned)k_out && Sr[r + 1] < (unsigned)k_out) {
                sT1 = (unsigned)(base + r);
                sAbove1 = Sr[r + 1];
            }
    }
    __syncthreads();
    const unsigned T1 = sT1, above1 = sAbove1;

    // Pass 2: low byte of maxima within bin T1
#pragma unroll
    for (int q = 0; q < 4; ++q) hist4[q][t] = 0;
    __syncthreads();
    if (tmax && (tmax >> 8) == T1) atomicAdd(&hist4[w][tmax & 255u], 1u);
    __syncthreads();
    if (w == 0) {
        unsigned need = (unsigned)k_out - above1;
        int base = lane * 4;
        unsigned h[4];
#pragma unroll
        for (int r = 0; r < 4; ++r)
            h[r] = hist4[0][base + r] + hist4[1][base + r] +
                   hist4[2][base + r] + hist4[3][base + r];
        unsigned lsum = h[0] + h[1] + h[2] + h[3];
        unsigned suf = lsum;
#pragma unroll
        for (int off = 1; off < 64; off <<= 1) {
            unsigned o = __shfl_down(suf, off, 64);
            suf += (lane + off < 64) ? o : 0u;
        }
        unsigned Sr[5];
        Sr[4] = suf - lsum;
#pragma unroll
        for (int r = 3; r >= 0; --r) Sr[r] = Sr[r + 1] + h[r];
#pragma unroll
        for (int r = 0; r < 4; ++r)
            if (Sr[r] >= need && Sr[r + 1] < need)
                sT2 = (unsigned)(base + r);
    }
    __syncthreads();
    const unsigned Lt = (T1 << 8) | sT2;   // k-th largest thread-max (or 0)

    // Compact all row values >= Lt
#pragma unroll
    for (int s = 0; s < 32; ++s) {
        unsigned m = m16[s];
        if (m && m >= Lt) {
            unsigned idx = atomicAdd(&cand_cnt, 1u);
            if (idx < CAND_CAP) {
                int j = jbase + s;
                cand[idx] = (m << 13) | (unsigned)(8191 - j);
            }
        }
    }
    __syncthreads();

    // Rank-by-counting extraction (keys unique -> ranks unique)
    const int m = (cand_cnt < CAND_CAP) ? (int)cand_cnt : CAND_CAP;
    const int reals = (k_out < nval) ? k_out : nval;
    for (int c = t; c < m; c += 256) {
        unsigned key = cand[c];
        int rank = 0;
        for (int x = 0; x < m; ++x) rank += (cand[x] > key) ? 1 : 0;
        if (rank < reals) {
            out_s[(size_t)i * k_out + rank] = scrub(inv_mono16(key >> 13));
            out_i[(size_t)i * k_out + rank] = (float)(8191 - (int)(key & 0x1FFFu));
        }
    }
    for (int r = reals + t; r < k_out; r += 256) {
        out_s[(size_t)i * k_out + r] = -1.0e30f;
        out_i[(size_t)i * k_out + r] = (float)r;
    }
}

extern "C" void kernel_launch(void* const* d_in, const int* in_sizes, int n_in,
                              void* d_out, int out_size, void* d_ws, size_t ws_size,
                              hipStream_t stream)
{
    const float* mentions = (const float*)d_in[0];   // [N x F]
    const float* W        = (const float*)d_in[1];   // [F x F]
    const float* bias     = (const float*)d_in[2];   // [F]

    const int F = in_sizes[2] > 0 ? in_sizes[2] : 1;
    const int N = in_sizes[0] / F;
    const int k_out = (N > 0) ? out_size / (2 * N) : 0;

    float* out_s = (float*)d_out;
    float* out_i = out_s + (size_t)N * k_out;

    prefill_kernel<<<256, 256, 0, stream>>>((float*)d_out, out_size);
    if (N <= 0 || k_out <= 0 || N > MAXN) return;

    dim3 blk(256);
    const bool tile_ok = (N % 128 == 0) && (F % 128 == 0);

    if (tile_ok) {
        // ws layout (bf16): Mb | Wb | Pb | sbuf
        ushort_t* Mb = (ushort_t*)d_ws;                    // N*F
        ushort_t* Wb = Mb + (size_t)N * F;                 // F*F
        ushort_t* Pb = Wb + (size_t)F * F;                 // N*F
        size_t fixed = ((size_t)2 * N * F + (size_t)F * F) * sizeof(ushort_t);
        size_t off = (fixed + 255) & ~(size_t)255;
        ushort_t* sbuf = (ushort_t*)((char*)d_ws + off);

        int chunk = N;
        while (chunk > 128 && off + (size_t)chunk * N * sizeof(ushort_t) > ws_size)
            chunk >>= 1;

        if (off + (size_t)chunk * N * sizeof(ushort_t) <= ws_size) {
            cast_bf16_kernel<<<(N * F / 8 + 255) / 256, blk, 0, stream>>>(
                mentions, Mb, N * F);
            cast_bf16_kernel<<<(F * F / 8 + 255) / 256, blk, 0, stream>>>(
                W, Wb, F * F);

            // GEMM1: Pb = bf16(mentions @ W^T + b)   [N x F]  (2D grid, tri=0)
            gemm_bf16_nt<<<dim3(F / 128, N / 128), blk, 0, stream>>>(
                Mb, Wb, bias, Pb, F, F, 0, 0);

            // GEMM2 (packed triangular grid, chunked) + top-k
            for (int r0 = 0; r0 < N; r0 += chunk) {
                int rows = (N - r0 < chunk) ? (N - r0) : chunk;
                int nby = rows / 128, base = r0 / 128;
                int T = nby * base + nby * (nby + 1) / 2;   // live tiles only
                gemm_bf16_nt<<<dim3(T, 1), blk, 0, stream>>>(
                    Pb + (size_t)r0 * F, Mb, nullptr, sbuf, F, N, base, 1);
                topk_kernel<<<rows, blk, 0, stream>>>(sbuf, N, r0, k_out, out_s, out_i);
            }
            return;
        }
    }

    // ---- fallback: naive f32 GEMMs + f32->bf16 cast of the score chunk ----
    {
        float* projf = (float*)d_ws;                           // N*F f32
        size_t o1 = (((size_t)N * F * sizeof(float)) + 255) & ~(size_t)255;
        float* sf = (float*)((char*)d_ws + o1);                // chunk*N f32
        int chunk = ((N + 127) / 128) * 128;
        while (chunk > 128 &&
               o1 + (size_t)chunk * N * (sizeof(float) + sizeof(ushort_t)) > ws_size)
            chunk >>= 1;
        size_t o2 = o1 + (((size_t)chunk * N * sizeof(float) + 255) & ~(size_t)255);
        ushort_t* sb = (ushort_t*)((char*)d_ws + o2);          // chunk*N bf16

        gemm_nt_naive<<<dim3((F + 15) / 16, (N + 15) / 16), blk, 0, stream>>>(
            mentions, W, bias, projf, F, F, N, F);
        for (int r0 = 0; r0 < N; r0 += chunk) {
            int rows = (N - r0 < chunk) ? (N - r0) : chunk;
            gemm_nt_naive<<<dim3((r0 + rows + 15) / 16, (rows + 15) / 16), blk, 0, stream>>>(
                projf + (size_t)r0 * F, mentions, nullptr, sf, F, N, rows, r0 + rows);
            cast_bf16_n_kernel<<<1024, blk, 0, stream>>>(sf, sb, (size_t)rows * N);
            topk_kernel<<<rows, blk, 0, stream>>>(sb, N, r0, k_out, out_s, out_i);
        }
    }
}

// Round 13
// 256.632 us; speedup vs baseline: 1.3342x; 1.3342x over previous
//
#include <hip/hip_runtime.h>

typedef unsigned short ushort_t;
typedef __attribute__((ext_vector_type(8))) short bf16x8;    // 8 bf16 = 4 VGPRs
typedef __attribute__((ext_vector_type(16))) float f32x16;   // 32x32 MFMA acc

#define MAXN 8192
#define CAND_CAP 2048

// ---- zero-prefill d_out (safety) ----
__global__ void prefill_kernel(float* __restrict__ out, int n) {
    for (int i = blockIdx.x * 256 + threadIdx.x; i < n; i += gridDim.x * 256)
        out[i] = 0.0f;
}

// ---- f32 -> bf16 cast (RNE), 8/thread ----
__global__ __launch_bounds__(256) void cast_bf16_kernel(
    const float* __restrict__ in, ushort_t* __restrict__ out, int n)
{
    int i = (blockIdx.x * 256 + threadIdx.x) * 8;
    if (i >= n) return;
    ushort_t o[8];
#pragma unroll
    for (int q = 0; q < 8; ++q) {
        unsigned u = __float_as_uint(in[i + q]);
        o[q] = (ushort_t)((u + 0x7FFFu + ((u >> 16) & 1u)) >> 16);
    }
    *(ushort4*)(out + i)     = make_ushort4(o[0], o[1], o[2], o[3]);
    *(ushort4*)(out + i + 4) = make_ushort4(o[4], o[5], o[6], o[7]);
}

// async global->LDS, 16B per lane; lds dest = wave-uniform base + lane*16
__device__ __forceinline__ void gload_lds16(const ushort_t* g, void* lds) {
    __builtin_amdgcn_global_load_lds(
        (const __attribute__((address_space(1))) unsigned int*)g,
        (__attribute__((address_space(3))) unsigned int*)lds, 16, 0, 0);
}

// ---- bf16 MFMA NT GEMM: C[i][j] = bf16(sum_k A[i][k]*B[j][k] (+bias[j])) ----
// 128x128 block tile, BK=64, 4 waves 2x2; wave tile 64x64 = 2x2 of 32x32x16.
// ~124 unified VGPRs, __launch_bounds__(256,4) -> 4 blocks/CU.
// tri=1: PACKED triangular grid — blockIdx.x flat over live tiles only.
// LDS 16B-slot swizzle: slot(m,kq) = m*8 + (kq ^ (m&7)).
__global__ __launch_bounds__(256, 4) void gemm_bf16_nt(
    const ushort_t* __restrict__ A, const ushort_t* __restrict__ B,
    const float* __restrict__ bias, ushort_t* __restrict__ C,
    int K, int ldc, int tbase, int tri)
{
    int bx, by;
    if (tri) {
        int f = blockIdx.x;
        int b = 0, off = 0;
        while (off + tbase + b + 1 <= f) { off += tbase + b + 1; ++b; }
        by = b; bx = f - off;
    } else {
        bx = blockIdx.x; by = blockIdx.y;
    }
    const int j0 = bx * 128;

    __shared__ __align__(16) ushort_t sA[128 * 64];
    __shared__ __align__(16) ushort_t sB[128 * 64];

    const int tid   = threadIdx.x;
    const int lane  = tid & 63;
    const int w     = tid >> 6;
    const int wr    = (w >> 1) * 64;
    const int wc    = (w & 1) * 64;
    const int l31   = lane & 31;
    const int khalf = lane >> 5;

    const ushort_t* Ab = A + (size_t)by * 128 * K;
    const ushort_t* Bb = B + (size_t)bx * 128 * K;

    f32x16 acc[2][2];
#pragma unroll
    for (int r = 0; r < 2; ++r)
#pragma unroll
        for (int c = 0; c < 2; ++c)
#pragma unroll
            for (int e = 0; e < 16; ++e) acc[r][c][e] = 0.0f;

    for (int k0 = 0; k0 < K; k0 += 64) {
#pragma unroll
        for (int qq = 0; qq < 4; ++qq) {
            int id = tid + qq * 256;           // 0..1023
            int m  = id >> 3;
            int kc = ((id & 7) ^ (m & 7)) * 8;
            unsigned lb = (unsigned)(((tid & ~63) + qq * 256) * 16);
            gload_lds16(Ab + (size_t)m * K + k0 + kc, (char*)sA + lb);
            gload_lds16(Bb + (size_t)m * K + k0 + kc, (char*)sB + lb);
        }
        __syncthreads();

#pragma unroll
        for (int h = 0; h < 4; ++h) {
            const int kq = h * 2 + khalf;
            bf16x8 fa[2], fb[2];
#pragma unroll
            for (int r = 0; r < 2; ++r) {
                int m = wr + r * 32 + l31;
                fa[r] = *(const bf16x8*)&sA[(m * 8 + (kq ^ (m & 7))) * 8];
            }
#pragma unroll
            for (int c = 0; c < 2; ++c) {
                int m = wc + c * 32 + l31;
                fb[c] = *(const bf16x8*)&sB[(m * 8 + (kq ^ (m & 7))) * 8];
            }
#pragma unroll
            for (int r = 0; r < 2; ++r)
#pragma unroll
                for (int c = 0; c < 2; ++c)
                    acc[r][c] = __builtin_amdgcn_mfma_f32_32x32x16_bf16(
                        fa[r], fb[c], acc[r][c], 0, 0, 0);
        }
        __syncthreads();
    }

    // Epilogue. 32x32 C/D layout (m74/m101): col = lane&31,
    // row = (reg&3) + 8*(reg>>2) + 4*(lane>>5). Store bf16 RNE.
#pragma unroll
    for (int r = 0; r < 2; ++r) {
#pragma unroll
        for (int c = 0; c < 2; ++c) {
            int colg = j0 + wc + c * 32 + l31;
            float bv = bias ? bias[colg] : 0.0f;
#pragma unroll
            for (int reg = 0; reg < 16; ++reg) {
                int rowl = (reg & 3) + 8 * (reg >> 2) + 4 * khalf;
                int row = by * 128 + wr + r * 32 + rowl;   // local row
                float v = acc[r][c][reg] + bv;
                unsigned u = __float_as_uint(v);
                C[(size_t)row * ldc + colg] =
                    (ushort_t)((u + 0x7FFFu + ((u >> 16) & 1u)) >> 16);
            }
        }
    }
}

// ---- fully-guarded naive fp32 NT GEMM -> f32 C (fallback only) ----
__global__ __launch_bounds__(256) void gemm_nt_naive(
    const float* __restrict__ A, const float* __restrict__ B,
    const float* __restrict__ bias, float* __restrict__ C,
    int K, int ldc, int rows, int cols)
{
    int j = blockIdx.x * 16 + (threadIdx.x & 15);
    int i = blockIdx.y * 16 + (threadIdx.x >> 4);
    if (i >= rows || j >= cols) return;
    float acc = bias ? bias[j] : 0.0f;
    const float* Ar = A + (size_t)i * K;
    const float* Br = B + (size_t)j * K;
    for (int k = 0; k < K; ++k) acc = fmaf(Ar[k], Br[k], acc);
    C[(size_t)i * ldc + j] = acc;
}

// ---- f32 -> bf16 strip cast (fallback) ----
__global__ __launch_bounds__(256) void cast_bf16_n_kernel(
    const float* __restrict__ in, ushort_t* __restrict__ out, size_t n)
{
    size_t i = (size_t)blockIdx.x * 256 + threadIdx.x;
    for (; i < n; i += (size_t)gridDim.x * 256) {
        unsigned u = __float_as_uint(in[i]);
        out[i] = (ushort_t)((u + 0x7FFFu + ((u >> 16) & 1u)) >> 16);
    }
}

// ---- threshold-pruned top-k per row on bf16 scores ----
__device__ __forceinline__ unsigned mono16(unsigned b) {
    return (b & 0x8000u) ? (~b & 0xFFFFu) : (b | 0x8000u);
}
__device__ __forceinline__ float inv_mono16(unsigned m) {
    unsigned b = (m & 0x8000u) ? (m & 0x7FFFu) : (~m & 0xFFFFu);
    return __uint_as_float(b << 16);
}
__device__ __forceinline__ float scrub(float v) {
    unsigned u = __float_as_uint(v);
    if (((u >> 23) & 0xFFu) == 0xFFu) return -1.0e30f;
    if (v < -1.0e37f) return -1.0e30f;
    return v;
}

// One block per row i = row_offset + blockIdx.x; S rows bf16, width N.
// STRIDED ownership (round-12 post-mortem): thread t owns j = t, t+256, ...
// so every row with nval >= k has min(nval,256) populated thread-maxima and
// the k-th-largest-thread-max threshold L yields m = count(>=L) ~ 50-100
// for ALL row sizes (round 12's contiguous blocks gave L=0 and m~1500 for
// rows nval<1568 -> O(m^2) rank-by-count blowup = the regression).
//  1. per-thread register max (strided, wave-coalesced loads, no atomics),
//  2. radix-select k-th largest of the 256 maxima (<=256 atomics) -> L.
//     Guarantee: >=k threads have max >= L, each contributes >=1 value >= L.
//  3. compact values >= L, rank-by-count (keys unique).
// Key = (mono16<<13)|(8191-j): max = max score, ties -> smaller j (JAX).
__global__ __launch_bounds__(256) void topk_kernel(
    const ushort_t* __restrict__ S, int N, int row_offset, int k_out,
    float* __restrict__ out_s, float* __restrict__ out_i)
{
    const int i = row_offset + blockIdx.x;
    const ushort_t* row = S + (size_t)blockIdx.x * N;
    const int t = threadIdx.x;
    const int lane = t & 63;
    const int w = t >> 6;
    const int nval = (i < N) ? i : N;

    __shared__ unsigned hist4[4][257];
    __shared__ unsigned cand[CAND_CAP];
    __shared__ unsigned cand_cnt;
    __shared__ unsigned sT1, sAbove1, sT2;

    unsigned m16[32];
    unsigned tmax = 0;
#pragma unroll
    for (int s = 0; s < 32; ++s) {
        int j = t + (s << 8);
        unsigned m = 0;
        if (j < nval) m = mono16(row[j]);
        m16[s] = m;
        if (m > tmax) tmax = m;
    }

    if (t == 0) { sT1 = 0; sAbove1 = 0; sT2 = 0; cand_cnt = 0; }
#pragma unroll
    for (int q = 0; q < 4; ++q) hist4[q][t] = 0;
    __syncthreads();

    // Pass 1: histogram of thread-maxima top bytes (ONE atomic per thread)
    if (tmax) atomicAdd(&hist4[w][tmax >> 8], 1u);
    __syncthreads();
    if (w == 0) {
        int base = lane * 4;
        unsigned h[4];
#pragma unroll
        for (int r = 0; r < 4; ++r)
            h[r] = hist4[0][base + r] + hist4[1][base + r] +
                   hist4[2][base + r] + hist4[3][base + r];
        unsigned lsum = h[0] + h[1] + h[2] + h[3];
        unsigned suf = lsum;
#pragma unroll
        for (int off = 1; off < 64; off <<= 1) {
            unsigned o = __shfl_down(suf, off, 64);
            suf += (lane + off < 64) ? o : 0u;
        }
        unsigned Sr[5];
        Sr[4] = suf - lsum;
#pragma unroll
        for (int r = 3; r >= 0; --r) Sr[r] = Sr[r + 1] + h[r];
#pragma unroll
        for (int r = 0; r < 4; ++r)
            if (Sr[r] >= (unsigned)k_out && Sr[r + 1] < (unsigned)k_out) {
                sT1 = (unsigned)(base + r);
                sAbove1 = Sr[r + 1];
            }
    }
    __syncthreads();
    const unsigned T1 = sT1, above1 = sAbove1;

    // Pass 2: low byte of maxima within bin T1
#pragma unroll
    for (int q = 0; q < 4; ++q) hist4[q][t] = 0;
    __syncthreads();
    if (tmax && (tmax >> 8) == T1) atomicAdd(&hist4[w][tmax & 255u], 1u);
    __syncthreads();
    if (w == 0) {
        unsigned need = (unsigned)k_out - above1;
        int base = lane * 4;
        unsigned h[4];
#pragma unroll
        for (int r = 0; r < 4; ++r)
            h[r] = hist4[0][base + r] + hist4[1][base + r] +
                   hist4[2][base + r] + hist4[3][base + r];
        unsigned lsum = h[0] + h[1] + h[2] + h[3];
        unsigned suf = lsum;
#pragma unroll
        for (int off = 1; off < 64; off <<= 1) {
            unsigned o = __shfl_down(suf, off, 64);
            suf += (lane + off < 64) ? o : 0u;
        }
        unsigned Sr[5];
        Sr[4] = suf - lsum;
#pragma unroll
        for (int r = 3; r >= 0; --r) Sr[r] = Sr[r + 1] + h[r];
#pragma unroll
        for (int r = 0; r < 4; ++r)
            if (Sr[r] >= need && Sr[r + 1] < need)
                sT2 = (unsigned)(base + r);
    }
    __syncthreads();
    const unsigned Lt = (T1 << 8) | sT2;   // k-th largest thread-max (or 0)

    // Compact all row values >= Lt
#pragma unroll
    for (int s = 0; s < 32; ++s) {
        unsigned m = m16[s];
        if (m && m >= Lt) {
            unsigned idx = atomicAdd(&cand_cnt, 1u);
            if (idx < CAND_CAP) {
                int j = t + (s << 8);
                cand[idx] = (m << 13) | (unsigned)(8191 - j);
            }
        }
    }
    __syncthreads();

    // Rank-by-counting extraction (keys unique -> ranks unique)
    const int m = (cand_cnt < CAND_CAP) ? (int)cand_cnt : CAND_CAP;
    const int reals = (k_out < nval) ? k_out : nval;
    for (int c = t; c < m; c += 256) {
        unsigned key = cand[c];
        int rank = 0;
        for (int x = 0; x < m; ++x) rank += (cand[x] > key) ? 1 : 0;
        if (rank < reals) {
            out_s[(size_t)i * k_out + rank] = scrub(inv_mono16(key >> 13));
            out_i[(size_t)i * k_out + rank] = (float)(8191 - (int)(key & 0x1FFFu));
        }
    }
    for (int r = reals + t; r < k_out; r += 256) {
        out_s[(size_t)i * k_out + r] = -1.0e30f;
        out_i[(size_t)i * k_out + r] = (float)r;
    }
}

extern "C" void kernel_launch(void* const* d_in, const int* in_sizes, int n_in,
                              void* d_out, int out_size, void* d_ws, size_t ws_size,
                              hipStream_t stream)
{
    const float* mentions = (const float*)d_in[0];   // [N x F]
    const float* W        = (const float*)d_in[1];   // [F x F]
    const float* bias     = (const float*)d_in[2];   // [F]

    const int F = in_sizes[2] > 0 ? in_sizes[2] : 1;
    const int N = in_sizes[0] / F;
    const int k_out = (N > 0) ? out_size / (2 * N) : 0;

    float* out_s = (float*)d_out;
    float* out_i = out_s + (size_t)N * k_out;

    prefill_kernel<<<256, 256, 0, stream>>>((float*)d_out, out_size);
    if (N <= 0 || k_out <= 0 || N > MAXN) return;

    dim3 blk(256);
    const bool tile_ok = (N % 128 == 0) && (F % 128 == 0);

    if (tile_ok) {
        // ws layout (bf16): Mb | Wb | Pb | sbuf
        ushort_t* Mb = (ushort_t*)d_ws;                    // N*F
        ushort_t* Wb = Mb + (size_t)N * F;                 // F*F
        ushort_t* Pb = Wb + (size_t)F * F;                 // N*F
        size_t fixed = ((size_t)2 * N * F + (size_t)F * F) * sizeof(ushort_t);
        size_t off = (fixed + 255) & ~(size_t)255;
        ushort_t* sbuf = (ushort_t*)((char*)d_ws + off);

        int chunk = N;
        while (chunk > 128 && off + (size_t)chunk * N * sizeof(ushort_t) > ws_size)
            chunk >>= 1;

        if (off + (size_t)chunk * N * sizeof(ushort_t) <= ws_size) {
            cast_bf16_kernel<<<(N * F / 8 + 255) / 256, blk, 0, stream>>>(
                mentions, Mb, N * F);
            cast_bf16_kernel<<<(F * F / 8 + 255) / 256, blk, 0, stream>>>(
                W, Wb, F * F);

            // GEMM1: Pb = bf16(mentions @ W^T + b)   [N x F]  (2D grid, tri=0)
            gemm_bf16_nt<<<dim3(F / 128, N / 128), blk, 0, stream>>>(
                Mb, Wb, bias, Pb, F, F, 0, 0);

            // GEMM2 (packed triangular grid, chunked) + top-k
            for (int r0 = 0; r0 < N; r0 += chunk) {
                int rows = (N - r0 < chunk) ? (N - r0) : chunk;
                int nby = rows / 128, base = r0 / 128;
                int T = nby * base + nby * (nby + 1) / 2;   // live tiles only
                gemm_bf16_nt<<<dim3(T, 1), blk, 0, stream>>>(
                    Pb + (size_t)r0 * F, Mb, nullptr, sbuf, F, N, base, 1);
                topk_kernel<<<rows, blk, 0, stream>>>(sbuf, N, r0, k_out, out_s, out_i);
            }
            return;
        }
    }

    // ---- fallback: naive f32 GEMMs + f32->bf16 cast of the score chunk ----
    {
        float* projf = (float*)d_ws;                           // N*F f32
        size_t o1 = (((size_t)N * F * sizeof(float)) + 255) & ~(size_t)255;
        float* sf = (float*)((char*)d_ws + o1);                // chunk*N f32
        int chunk = ((N + 127) / 128) * 128;
        while (chunk > 128 &&
               o1 + (size_t)chunk * N * (sizeof(float) + sizeof(ushort_t)) > ws_size)
            chunk >>= 1;
        size_t o2 = o1 + (((size_t)chunk * N * sizeof(float) + 255) & ~(size_t)255);
        ushort_t* sb = (ushort_t*)((char*)d_ws + o2);          // chunk*N bf16

        gemm_nt_naive<<<dim3((F + 15) / 16, (N + 15) / 16), blk, 0, stream>>>(
            mentions, W, bias, projf, F, F, N, F);
        for (int r0 = 0; r0 < N; r0 += chunk) {
            int rows = (N - r0 < chunk) ? (N - r0) : chunk;
            gemm_nt_naive<<<dim3((r0 + rows + 15) / 16, (rows + 15) / 16), blk, 0, stream>>>(
                projf + (size_t)r0 * F, mentions, nullptr, sf, F, N, rows, r0 + rows);
            cast_bf16_n_kernel<<<1024, blk, 0, stream>>>(sf, sb, (size_t)rows * N);
            topk_kernel<<<rows, blk, 0, stream>>>(sb, N, r0, k_out, out_s, out_i);
        }
    }
}

// Round 14
// 251.140 us; speedup vs baseline: 1.3633x; 1.0219x over previous
//
#include <hip/hip_runtime.h>

typedef unsigned short ushort_t;
typedef __attribute__((ext_vector_type(8))) short bf16x8;    // 8 bf16 = 4 VGPRs
typedef __attribute__((ext_vector_type(16))) float f32x16;   // 32x32 MFMA acc

#define MAXN 8192
#define CAND_CAP 2048
#define CHUNK_CAP 4096   // keep sbuf (chunk*N*2B) + inputs inside 256MB L3

// ---- zero-prefill d_out (safety) ----
__global__ void prefill_kernel(float* __restrict__ out, int n) {
    for (int i = blockIdx.x * 256 + threadIdx.x; i < n; i += gridDim.x * 256)
        out[i] = 0.0f;
}

// ---- f32 -> bf16 cast (RNE), 8/thread ----
__global__ __launch_bounds__(256) void cast_bf16_kernel(
    const float* __restrict__ in, ushort_t* __restrict__ out, int n)
{
    int i = (blockIdx.x * 256 + threadIdx.x) * 8;
    if (i >= n) return;
    ushort_t o[8];
#pragma unroll
    for (int q = 0; q < 8; ++q) {
        unsigned u = __float_as_uint(in[i + q]);
        o[q] = (ushort_t)((u + 0x7FFFu + ((u >> 16) & 1u)) >> 16);
    }
    *(ushort4*)(out + i)     = make_ushort4(o[0], o[1], o[2], o[3]);
    *(ushort4*)(out + i + 4) = make_ushort4(o[4], o[5], o[6], o[7]);
}

// async global->LDS, 16B per lane; lds dest = wave-uniform base + lane*16
__device__ __forceinline__ void gload_lds16(const ushort_t* g, void* lds) {
    __builtin_amdgcn_global_load_lds(
        (const __attribute__((address_space(1))) unsigned int*)g,
        (__attribute__((address_space(3))) unsigned int*)lds, 16, 0, 0);
}

// ---- bf16 MFMA NT GEMM: C[i][j] = bf16(sum_k A[i][k]*B[j][k] (+bias[j])) ----
// 128x128 block tile, BK=64, 4 waves 2x2; wave tile 64x64 = 2x2 of 32x32x16.
// ~124 unified VGPRs, __launch_bounds__(256,4) -> 4 blocks/CU.
// tri=1: PACKED triangular grid — blockIdx.x flat over live tiles only.
// LDS 16B-slot swizzle: slot(m,kq) = m*8 + (kq ^ (m&7)).
__global__ __launch_bounds__(256, 4) void gemm_bf16_nt(
    const ushort_t* __restrict__ A, const ushort_t* __restrict__ B,
    const float* __restrict__ bias, ushort_t* __restrict__ C,
    int K, int ldc, int tbase, int tri)
{
    int bx, by;
    if (tri) {
        int f = blockIdx.x;
        int b = 0, off = 0;
        while (off + tbase + b + 1 <= f) { off += tbase + b + 1; ++b; }
        by = b; bx = f - off;
    } else {
        bx = blockIdx.x; by = blockIdx.y;
    }
    const int j0 = bx * 128;

    __shared__ __align__(16) ushort_t sA[128 * 64];
    __shared__ __align__(16) ushort_t sB[128 * 64];

    const int tid   = threadIdx.x;
    const int lane  = tid & 63;
    const int w     = tid >> 6;
    const int wr    = (w >> 1) * 64;
    const int wc    = (w & 1) * 64;
    const int l31   = lane & 31;
    const int khalf = lane >> 5;

    const ushort_t* Ab = A + (size_t)by * 128 * K;
    const ushort_t* Bb = B + (size_t)bx * 128 * K;

    f32x16 acc[2][2];
#pragma unroll
    for (int r = 0; r < 2; ++r)
#pragma unroll
        for (int c = 0; c < 2; ++c)
#pragma unroll
            for (int e = 0; e < 16; ++e) acc[r][c][e] = 0.0f;

    for (int k0 = 0; k0 < K; k0 += 64) {
#pragma unroll
        for (int qq = 0; qq < 4; ++qq) {
            int id = tid + qq * 256;           // 0..1023
            int m  = id >> 3;
            int kc = ((id & 7) ^ (m & 7)) * 8;
            unsigned lb = (unsigned)(((tid & ~63) + qq * 256) * 16);
            gload_lds16(Ab + (size_t)m * K + k0 + kc, (char*)sA + lb);
            gload_lds16(Bb + (size_t)m * K + k0 + kc, (char*)sB + lb);
        }
        __syncthreads();

#pragma unroll
        for (int h = 0; h < 4; ++h) {
            const int kq = h * 2 + khalf;
            bf16x8 fa[2], fb[2];
#pragma unroll
            for (int r = 0; r < 2; ++r) {
                int m = wr + r * 32 + l31;
                fa[r] = *(const bf16x8*)&sA[(m * 8 + (kq ^ (m & 7))) * 8];
            }
#pragma unroll
            for (int c = 0; c < 2; ++c) {
                int m = wc + c * 32 + l31;
                fb[c] = *(const bf16x8*)&sB[(m * 8 + (kq ^ (m & 7))) * 8];
            }
#pragma unroll
            for (int r = 0; r < 2; ++r)
#pragma unroll
                for (int c = 0; c < 2; ++c)
                    acc[r][c] = __builtin_amdgcn_mfma_f32_32x32x16_bf16(
                        fa[r], fb[c], acc[r][c], 0, 0, 0);
        }
        __syncthreads();
    }

    // Epilogue. 32x32 C/D layout (m74/m101): col = lane&31,
    // row = (reg&3) + 8*(reg>>2) + 4*(lane>>5). Store bf16 RNE.
#pragma unroll
    for (int r = 0; r < 2; ++r) {
#pragma unroll
        for (int c = 0; c < 2; ++c) {
            int colg = j0 + wc + c * 32 + l31;
            float bv = bias ? bias[colg] : 0.0f;
#pragma unroll
            for (int reg = 0; reg < 16; ++reg) {
                int rowl = (reg & 3) + 8 * (reg >> 2) + 4 * khalf;
                int row = by * 128 + wr + r * 32 + rowl;   // local row
                float v = acc[r][c][reg] + bv;
                unsigned u = __float_as_uint(v);
                C[(size_t)row * ldc + colg] =
                    (ushort_t)((u + 0x7FFFu + ((u >> 16) & 1u)) >> 16);
            }
        }
    }
}

// ---- fully-guarded naive fp32 NT GEMM -> f32 C (fallback only) ----
__global__ __launch_bounds__(256) void gemm_nt_naive(
    const float* __restrict__ A, const float* __restrict__ B,
    const float* __restrict__ bias, float* __restrict__ C,
    int K, int ldc, int rows, int cols)
{
    int j = blockIdx.x * 16 + (threadIdx.x & 15);
    int i = blockIdx.y * 16 + (threadIdx.x >> 4);
    if (i >= rows || j >= cols) return;
    float acc = bias ? bias[j] : 0.0f;
    const float* Ar = A + (size_t)i * K;
    const float* Br = B + (size_t)j * K;
    for (int k = 0; k < K; ++k) acc = fmaf(Ar[k], Br[k], acc);
    C[(size_t)i * ldc + j] = acc;
}

// ---- f32 -> bf16 strip cast (fallback) ----
__global__ __launch_bounds__(256) void cast_bf16_n_kernel(
    const float* __restrict__ in, ushort_t* __restrict__ out, size_t n)
{
    size_t i = (size_t)blockIdx.x * 256 + threadIdx.x;
    for (; i < n; i += (size_t)gridDim.x * 256) {
        unsigned u = __float_as_uint(in[i]);
        out[i] = (ushort_t)((u + 0x7FFFu + ((u >> 16) & 1u)) >> 16);
    }
}

// ---- threshold-pruned top-k per row on bf16 scores ----
__device__ __forceinline__ unsigned mono16(unsigned b) {
    return (b & 0x8000u) ? (~b & 0xFFFFu) : (b | 0x8000u);
}
__device__ __forceinline__ float inv_mono16(unsigned m) {
    unsigned b = (m & 0x8000u) ? (m & 0x7FFFu) : (~m & 0xFFFFu);
    return __uint_as_float(b << 16);
}
__device__ __forceinline__ float scrub(float v) {
    unsigned u = __float_as_uint(v);
    if (((u >> 23) & 0xFFu) == 0xFFu) return -1.0e30f;
    if (v < -1.0e37f) return -1.0e30f;
    return v;
}

// One block per row i = row_offset + blockIdx.x; S rows bf16, width N.
// Round-14: VECTORIZED ownership — thread t owns 4 chunks of 8 consecutive
// values: j = c*2048 + t*8 + e (c<4, e<8). Loads are uint4 (16B/lane, 1KB
// per wave-instr — round 13 used 2B/lane strided u16, 8x more load instrs).
// Thread still owns 32 values, so the k-th-largest-thread-max threshold L
// keeps m = count(>=L) ~ 55 for all row sizes (order stats independent of
// grouping); rows with <k populated maxima fall through to L=0 and
// nval < CAND_CAP holds there (nval < k*8*... <= 2048 worst case covered:
// if no bin reaches k_out, Lt=0 and m=nval<=CAND_CAP guarded by cap).
//  1. per-thread register max, no atomics;
//  2. radix-select k-th largest of 256 maxima -> L (guarantee: >=k threads
//     have max >= L, each contributes >=1 value >= L => count(>=L) >= k);
//  3. compact values >= L, rank-by-count (keys unique).
// Key = (mono16<<13)|(8191-j): max = max score, ties -> smaller j (JAX).
__global__ __launch_bounds__(256) void topk_kernel(
    const ushort_t* __restrict__ S, int N, int row_offset, int k_out,
    float* __restrict__ out_s, float* __restrict__ out_i)
{
    const int i = row_offset + blockIdx.x;
    const ushort_t* row = S + (size_t)blockIdx.x * N;
    const int t = threadIdx.x;
    const int lane = t & 63;
    const int w = t >> 6;
    const int nval = (i < N) ? i : N;
    const bool vec_ok = (N % 8) == 0;

    __shared__ unsigned hist4[4][257];
    __shared__ unsigned cand[CAND_CAP];
    __shared__ unsigned cand_cnt;
    __shared__ unsigned sT1, sAbove1, sT2;

    unsigned m16[32];
    unsigned tmax = 0;
#pragma unroll
    for (int c = 0; c < 4; ++c) {
        int jb = c * 2048 + t * 8;
        if (jb < nval) {
            ushort_t vv[8];
            if (vec_ok && jb + 8 <= N) {
                *(uint4*)vv = *(const uint4*)(row + jb);
            } else {
#pragma unroll
                for (int e = 0; e < 8; ++e) vv[e] = (jb + e < N) ? row[jb + e] : 0;
            }
#pragma unroll
            for (int e = 0; e < 8; ++e) {
                unsigned m = (jb + e < nval) ? mono16(vv[e]) : 0u;
                m16[c * 8 + e] = m;
                if (m > tmax) tmax = m;
            }
        } else {
#pragma unroll
            for (int e = 0; e < 8; ++e) m16[c * 8 + e] = 0u;
        }
    }

    if (t == 0) { sT1 = 0; sAbove1 = 0; sT2 = 0; cand_cnt = 0; }
#pragma unroll
    for (int q = 0; q < 4; ++q) hist4[q][t] = 0;
    __syncthreads();

    // Pass 1: histogram of thread-maxima top bytes (ONE atomic per thread)
    if (tmax) atomicAdd(&hist4[w][tmax >> 8], 1u);
    __syncthreads();
    if (w == 0) {
        int base = lane * 4;
        unsigned h[4];
#pragma unroll
        for (int r = 0; r < 4; ++r)
            h[r] = hist4[0][base + r] + hist4[1][base + r] +
                   hist4[2][base + r] + hist4[3][base + r];
        unsigned lsum = h[0] + h[1] + h[2] + h[3];
        unsigned suf = lsum;
#pragma unroll
        for (int off = 1; off < 64; off <<= 1) {
            unsigned o = __shfl_down(suf, off, 64);
            suf += (lane + off < 64) ? o : 0u;
        }
        unsigned Sr[5];
        Sr[4] = suf - lsum;
#pragma unroll
        for (int r = 3; r >= 0; --r) Sr[r] = Sr[r + 1] + h[r];
#pragma unroll
        for (int r = 0; r < 4; ++r)
            if (Sr[r] >= (unsigned)k_out && Sr[r + 1] < (unsigned)k_out) {
                sT1 = (unsigned)(base + r);
                sAbove1 = Sr[r + 1];
            }
    }
    __syncthreads();
    const unsigned T1 = sT1, above1 = sAbove1;

    // Pass 2: low byte of maxima within bin T1
#pragma unroll
    for (int q = 0; q < 4; ++q) hist4[q][t] = 0;
    __syncthreads();
    if (tmax && (tmax >> 8) == T1) atomicAdd(&hist4[w][tmax & 255u], 1u);
    __syncthreads();
    if (w == 0) {
        unsigned need = (unsigned)k_out - above1;
        int base = lane * 4;
        unsigned h[4];
#pragma unroll
        for (int r = 0; r < 4; ++r)
            h[r] = hist4[0][base + r] + hist4[1][base + r] +
                   hist4[2][base + r] + hist4[3][base + r];
        unsigned lsum = h[0] + h[1] + h[2] + h[3];
        unsigned suf = lsum;
#pragma unroll
        for (int off = 1; off < 64; off <<= 1) {
            unsigned o = __shfl_down(suf, off, 64);
            suf += (lane + off < 64) ? o : 0u;
        }
        unsigned Sr[5];
        Sr[4] = suf - lsum;
#pragma unroll
        for (int r = 3; r >= 0; --r) Sr[r] = Sr[r + 1] + h[r];
#pragma unroll
        for (int r = 0; r < 4; ++r)
            if (Sr[r] >= need && Sr[r + 1] < need)
                sT2 = (unsigned)(base + r);
    }
    __syncthreads();
    const unsigned Lt = (T1 << 8) | sT2;   // k-th largest thread-max (or 0)

    // Compact all row values >= Lt
#pragma unroll
    for (int s = 0; s < 32; ++s) {
        unsigned m = m16[s];
        if (m && m >= Lt) {
            unsigned idx = atomicAdd(&cand_cnt, 1u);
            if (idx < CAND_CAP) {
                int j = (s >> 3) * 2048 + t * 8 + (s & 7);
                cand[idx] = (m << 13) | (unsigned)(8191 - j);
            }
        }
    }
    __syncthreads();

    // Rank-by-counting extraction (keys unique -> ranks unique)
    const int m = (cand_cnt < CAND_CAP) ? (int)cand_cnt : CAND_CAP;
    const int reals = (k_out < nval) ? k_out : nval;
    for (int c = t; c < m; c += 256) {
        unsigned key = cand[c];
        int rank = 0;
        for (int x = 0; x < m; ++x) rank += (cand[x] > key) ? 1 : 0;
        if (rank < reals) {
            out_s[(size_t)i * k_out + rank] = scrub(inv_mono16(key >> 13));
            out_i[(size_t)i * k_out + rank] = (float)(8191 - (int)(key & 0x1FFFu));
        }
    }
    for (int r = reals + t; r < k_out; r += 256) {
        out_s[(size_t)i * k_out + r] = -1.0e30f;
        out_i[(size_t)i * k_out + r] = (float)r;
    }
}

extern "C" void kernel_launch(void* const* d_in, const int* in_sizes, int n_in,
                              void* d_out, int out_size, void* d_ws, size_t ws_size,
                              hipStream_t stream)
{
    const float* mentions = (const float*)d_in[0];   // [N x F]
    const float* W        = (const float*)d_in[1];   // [F x F]
    const float* bias     = (const float*)d_in[2];   // [F]

    const int F = in_sizes[2] > 0 ? in_sizes[2] : 1;
    const int N = in_sizes[0] / F;
    const int k_out = (N > 0) ? out_size / (2 * N) : 0;

    float* out_s = (float*)d_out;
    float* out_i = out_s + (size_t)N * k_out;

    prefill_kernel<<<256, 256, 0, stream>>>((float*)d_out, out_size);
    if (N <= 0 || k_out <= 0 || N > MAXN) return;

    dim3 blk(256);
    const bool tile_ok = (N % 128 == 0) && (F % 128 == 0);

    if (tile_ok) {
        // ws layout (bf16): Mb | Wb | Pb | sbuf
        ushort_t* Mb = (ushort_t*)d_ws;                    // N*F
        ushort_t* Wb = Mb + (size_t)N * F;                 // F*F
        ushort_t* Pb = Wb + (size_t)F * F;                 // N*F
        size_t fixed = ((size_t)2 * N * F + (size_t)F * F) * sizeof(ushort_t);
        size_t off = (fixed + 255) & ~(size_t)255;
        ushort_t* sbuf = (ushort_t*)((char*)d_ws + off);

        // Cap chunk so sbuf + inputs stay L3-resident (round-13 post-mortem:
        // full-size sbuf writes evicted Pb/Mb -> 248 MB HBM refetch).
        int chunk = (N < CHUNK_CAP) ? N : CHUNK_CAP;
        while (chunk > 128 && off + (size_t)chunk * N * sizeof(ushort_t) > ws_size)
            chunk >>= 1;

        if (off + (size_t)chunk * N * sizeof(ushort_t) <= ws_size) {
            cast_bf16_kernel<<<(N * F / 8 + 255) / 256, blk, 0, stream>>>(
                mentions, Mb, N * F);
            cast_bf16_kernel<<<(F * F / 8 + 255) / 256, blk, 0, stream>>>(
                W, Wb, F * F);

            // GEMM1: Pb = bf16(mentions @ W^T + b)   [N x F]  (2D grid, tri=0)
            gemm_bf16_nt<<<dim3(F / 128, N / 128), blk, 0, stream>>>(
                Mb, Wb, bias, Pb, F, F, 0, 0);

            // GEMM2 (packed triangular grid, chunked) + top-k
            for (int r0 = 0; r0 < N; r0 += chunk) {
                int rows = (N - r0 < chunk) ? (N - r0) : chunk;
                int nby = rows / 128, base = r0 / 128;
                int T = nby * base + nby * (nby + 1) / 2;   // live tiles only
                gemm_bf16_nt<<<dim3(T, 1), blk, 0, stream>>>(
                    Pb + (size_t)r0 * F, Mb, nullptr, sbuf, F, N, base, 1);
                topk_kernel<<<rows, blk, 0, stream>>>(sbuf, N, r0, k_out, out_s, out_i);
            }
            return;
        }
    }

    // ---- fallback: naive f32 GEMMs + f32->bf16 cast of the score chunk ----
    {
        float* projf = (float*)d_ws;                           // N*F f32
        size_t o1 = (((size_t)N * F * sizeof(float)) + 255) & ~(size_t)255;
        float* sf = (float*)((char*)d_ws + o1);                // chunk*N f32
        int chunk = ((N + 127) / 128) * 128;
        while (chunk > 128 &&
               o1 + (size_t)chunk * N * (sizeof(float) + sizeof(ushort_t)) > ws_size)
            chunk >>= 1;
        size_t o2 = o1 + (((size_t)chunk * N * sizeof(float) + 255) & ~(size_t)255);
        ushort_t* sb = (ushort_t*)((char*)d_ws + o2);          // chunk*N bf16

        gemm_nt_naive<<<dim3((F + 15) / 16, (N + 15) / 16), blk, 0, stream>>>(
            mentions, W, bias, projf, F, F, N, F);
        for (int r0 = 0; r0 < N; r0 += chunk) {
            int rows = (N - r0 < chunk) ? (N - r0) : chunk;
            gemm_nt_naive<<<dim3((r0 + rows + 15) / 16, (rows + 15) / 16), blk, 0, stream>>>(
                projf + (size_t)r0 * F, mentions, nullptr, sf, F, N, rows, r0 + rows);
            cast_bf16_n_kernel<<<1024, blk, 0, stream>>>(sf, sb, (size_t)rows * N);
            topk_kernel<<<rows, blk, 0, stream>>>(sb, N, r0, k_out, out_s, out_i);
        }
    }
}

// Round 15
// 235.632 us; speedup vs baseline: 1.4531x; 1.0658x over previous
//
#include <hip/hip_runtime.h>

typedef unsigned short ushort_t;
typedef __attribute__((ext_vector_type(8))) short bf16x8;    // 8 bf16 = 4 VGPRs
typedef __attribute__((ext_vector_type(16))) float f32x16;   // 32x32 MFMA acc

#define MAXN 8192
#define CAND_CAP 2048
#define CHUNK_CAP 8192   // round-15: single GEMM2 dispatch beats 2 half-size
                         // ones (round 13 vs 14: 100 us vs 2x79 — the split's
                         // 528-block first chunk left half the GPU idle and
                         // the L3-residency theory didn't pay)

// ---- zero-prefill d_out (safety) ----
__global__ void prefill_kernel(float* __restrict__ out, int n) {
    for (int i = blockIdx.x * 256 + threadIdx.x; i < n; i += gridDim.x * 256)
        out[i] = 0.0f;
}

// ---- f32 -> bf16 cast (RNE), 8/thread ----
__global__ __launch_bounds__(256) void cast_bf16_kernel(
    const float* __restrict__ in, ushort_t* __restrict__ out, int n)
{
    int i = (blockIdx.x * 256 + threadIdx.x) * 8;
    if (i >= n) return;
    ushort_t o[8];
#pragma unroll
    for (int q = 0; q < 8; ++q) {
        unsigned u = __float_as_uint(in[i + q]);
        o[q] = (ushort_t)((u + 0x7FFFu + ((u >> 16) & 1u)) >> 16);
    }
    *(ushort4*)(out + i)     = make_ushort4(o[0], o[1], o[2], o[3]);
    *(ushort4*)(out + i + 4) = make_ushort4(o[4], o[5], o[6], o[7]);
}

// async global->LDS, 16B per lane; lds dest = wave-uniform base + lane*16
__device__ __forceinline__ void gload_lds16(const ushort_t* g, void* lds) {
    __builtin_amdgcn_global_load_lds(
        (const __attribute__((address_space(1))) unsigned int*)g,
        (__attribute__((address_space(3))) unsigned int*)lds, 16, 0, 0);
}

// ---- bf16 MFMA NT GEMM: C[i][j] = bf16(sum_k A[i][k]*B[j][k] (+bias[j])) ----
// 128x128 block tile, BK=64, 4 waves 2x2; wave tile 64x64 = 2x2 of 32x32x16.
// ~124 unified VGPRs, __launch_bounds__(256,4) -> 4 blocks/CU.
// tri=1: PACKED triangular grid — blockIdx.x flat over live tiles only.
// LDS 16B-slot swizzle: slot(m,kq) = m*8 + (kq ^ (m&7)).
__global__ __launch_bounds__(256, 4) void gemm_bf16_nt(
    const ushort_t* __restrict__ A, const ushort_t* __restrict__ B,
    const float* __restrict__ bias, ushort_t* __restrict__ C,
    int K, int ldc, int tbase, int tri)
{
    int bx, by;
    if (tri) {
        int f = blockIdx.x;
        int b = 0, off = 0;
        while (off + tbase + b + 1 <= f) { off += tbase + b + 1; ++b; }
        by = b; bx = f - off;
    } else {
        bx = blockIdx.x; by = blockIdx.y;
    }
    const int j0 = bx * 128;

    __shared__ __align__(16) ushort_t sA[128 * 64];
    __shared__ __align__(16) ushort_t sB[128 * 64];

    const int tid   = threadIdx.x;
    const int lane  = tid & 63;
    const int w     = tid >> 6;
    const int wr    = (w >> 1) * 64;
    const int wc    = (w & 1) * 64;
    const int l31   = lane & 31;
    const int khalf = lane >> 5;

    const ushort_t* Ab = A + (size_t)by * 128 * K;
    const ushort_t* Bb = B + (size_t)bx * 128 * K;

    f32x16 acc[2][2];
#pragma unroll
    for (int r = 0; r < 2; ++r)
#pragma unroll
        for (int c = 0; c < 2; ++c)
#pragma unroll
            for (int e = 0; e < 16; ++e) acc[r][c][e] = 0.0f;

    for (int k0 = 0; k0 < K; k0 += 64) {
#pragma unroll
        for (int qq = 0; qq < 4; ++qq) {
            int id = tid + qq * 256;           // 0..1023
            int m  = id >> 3;
            int kc = ((id & 7) ^ (m & 7)) * 8;
            unsigned lb = (unsigned)(((tid & ~63) + qq * 256) * 16);
            gload_lds16(Ab + (size_t)m * K + k0 + kc, (char*)sA + lb);
            gload_lds16(Bb + (size_t)m * K + k0 + kc, (char*)sB + lb);
        }
        __syncthreads();

#pragma unroll
        for (int h = 0; h < 4; ++h) {
            const int kq = h * 2 + khalf;
            bf16x8 fa[2], fb[2];
#pragma unroll
            for (int r = 0; r < 2; ++r) {
                int m = wr + r * 32 + l31;
                fa[r] = *(const bf16x8*)&sA[(m * 8 + (kq ^ (m & 7))) * 8];
            }
#pragma unroll
            for (int c = 0; c < 2; ++c) {
                int m = wc + c * 32 + l31;
                fb[c] = *(const bf16x8*)&sB[(m * 8 + (kq ^ (m & 7))) * 8];
            }
#pragma unroll
            for (int r = 0; r < 2; ++r)
#pragma unroll
                for (int c = 0; c < 2; ++c)
                    acc[r][c] = __builtin_amdgcn_mfma_f32_32x32x16_bf16(
                        fa[r], fb[c], acc[r][c], 0, 0, 0);
        }
        __syncthreads();
    }

    // Epilogue. 32x32 C/D layout (m74/m101): col = lane&31,
    // row = (reg&3) + 8*(reg>>2) + 4*(lane>>5). Store bf16 RNE.
#pragma unroll
    for (int r = 0; r < 2; ++r) {
#pragma unroll
        for (int c = 0; c < 2; ++c) {
            int colg = j0 + wc + c * 32 + l31;
            float bv = bias ? bias[colg] : 0.0f;
#pragma unroll
            for (int reg = 0; reg < 16; ++reg) {
                int rowl = (reg & 3) + 8 * (reg >> 2) + 4 * khalf;
                int row = by * 128 + wr + r * 32 + rowl;   // local row
                float v = acc[r][c][reg] + bv;
                unsigned u = __float_as_uint(v);
                C[(size_t)row * ldc + colg] =
                    (ushort_t)((u + 0x7FFFu + ((u >> 16) & 1u)) >> 16);
            }
        }
    }
}

// ---- fully-guarded naive fp32 NT GEMM -> f32 C (fallback only) ----
__global__ __launch_bounds__(256) void gemm_nt_naive(
    const float* __restrict__ A, const float* __restrict__ B,
    const float* __restrict__ bias, float* __restrict__ C,
    int K, int ldc, int rows, int cols)
{
    int j = blockIdx.x * 16 + (threadIdx.x & 15);
    int i = blockIdx.y * 16 + (threadIdx.x >> 4);
    if (i >= rows || j >= cols) return;
    float acc = bias ? bias[j] : 0.0f;
    const float* Ar = A + (size_t)i * K;
    const float* Br = B + (size_t)j * K;
    for (int k = 0; k < K; ++k) acc = fmaf(Ar[k], Br[k], acc);
    C[(size_t)i * ldc + j] = acc;
}

// ---- f32 -> bf16 strip cast (fallback) ----
__global__ __launch_bounds__(256) void cast_bf16_n_kernel(
    const float* __restrict__ in, ushort_t* __restrict__ out, size_t n)
{
    size_t i = (size_t)blockIdx.x * 256 + threadIdx.x;
    for (; i < n; i += (size_t)gridDim.x * 256) {
        unsigned u = __float_as_uint(in[i]);
        out[i] = (ushort_t)((u + 0x7FFFu + ((u >> 16) & 1u)) >> 16);
    }
}

// ---- threshold-pruned top-k per row on bf16 scores ----
__device__ __forceinline__ unsigned mono16(unsigned b) {
    return (b & 0x8000u) ? (~b & 0xFFFFu) : (b | 0x8000u);
}
__device__ __forceinline__ float inv_mono16(unsigned m) {
    unsigned b = (m & 0x8000u) ? (m & 0x7FFFu) : (~m & 0xFFFFu);
    return __uint_as_float(b << 16);
}
__device__ __forceinline__ float scrub(float v) {
    unsigned u = __float_as_uint(v);
    if (((u >> 23) & 0xFFu) == 0xFFu) return -1.0e30f;
    if (v < -1.0e37f) return -1.0e30f;
    return v;
}

// One block per row i = row_offset + blockIdx.x; S rows bf16, width N.
// VECTORIZED ownership — thread t owns 4 chunks of 8 consecutive values:
// j = c*2048 + t*8 + e (uint4 loads, 1KB/wave-instr).
//  1. per-thread register max, no atomics;
//  2. radix-select k-th largest of 256 maxima -> L (guarantee: >=k threads
//     have max >= L, each contributes >=1 value >= L => count(>=L) >= k);
//  3. compact values >= L, rank-by-count (keys unique).
// Key = (mono16<<13)|(8191-j): max = max score, ties -> smaller j (JAX).
__global__ __launch_bounds__(256) void topk_kernel(
    const ushort_t* __restrict__ S, int N, int row_offset, int k_out,
    float* __restrict__ out_s, float* __restrict__ out_i)
{
    const int i = row_offset + blockIdx.x;
    const ushort_t* row = S + (size_t)blockIdx.x * N;
    const int t = threadIdx.x;
    const int lane = t & 63;
    const int w = t >> 6;
    const int nval = (i < N) ? i : N;
    const bool vec_ok = (N % 8) == 0;

    __shared__ unsigned hist4[4][257];
    __shared__ unsigned cand[CAND_CAP];
    __shared__ unsigned cand_cnt;
    __shared__ unsigned sT1, sAbove1, sT2;

    unsigned m16[32];
    unsigned tmax = 0;
#pragma unroll
    for (int c = 0; c < 4; ++c) {
        int jb = c * 2048 + t * 8;
        if (jb < nval) {
            ushort_t vv[8];
            if (vec_ok && jb + 8 <= N) {
                *(uint4*)vv = *(const uint4*)(row + jb);
            } else {
#pragma unroll
                for (int e = 0; e < 8; ++e) vv[e] = (jb + e < N) ? row[jb + e] : 0;
            }
#pragma unroll
            for (int e = 0; e < 8; ++e) {
                unsigned m = (jb + e < nval) ? mono16(vv[e]) : 0u;
                m16[c * 8 + e] = m;
                if (m > tmax) tmax = m;
            }
        } else {
#pragma unroll
            for (int e = 0; e < 8; ++e) m16[c * 8 + e] = 0u;
        }
    }

    if (t == 0) { sT1 = 0; sAbove1 = 0; sT2 = 0; cand_cnt = 0; }
#pragma unroll
    for (int q = 0; q < 4; ++q) hist4[q][t] = 0;
    __syncthreads();

    // Pass 1: histogram of thread-maxima top bytes (ONE atomic per thread)
    if (tmax) atomicAdd(&hist4[w][tmax >> 8], 1u);
    __syncthreads();
    if (w == 0) {
        int base = lane * 4;
        unsigned h[4];
#pragma unroll
        for (int r = 0; r < 4; ++r)
            h[r] = hist4[0][base + r] + hist4[1][base + r] +
                   hist4[2][base + r] + hist4[3][base + r];
        unsigned lsum = h[0] + h[1] + h[2] + h[3];
        unsigned suf = lsum;
#pragma unroll
        for (int off = 1; off < 64; off <<= 1) {
            unsigned o = __shfl_down(suf, off, 64);
            suf += (lane + off < 64) ? o : 0u;
        }
        unsigned Sr[5];
        Sr[4] = suf - lsum;
#pragma unroll
        for (int r = 3; r >= 0; --r) Sr[r] = Sr[r + 1] + h[r];
#pragma unroll
        for (int r = 0; r < 4; ++r)
            if (Sr[r] >= (unsigned)k_out && Sr[r + 1] < (unsigned)k_out) {
                sT1 = (unsigned)(base + r);
                sAbove1 = Sr[r + 1];
            }
    }
    __syncthreads();
    const unsigned T1 = sT1, above1 = sAbove1;

    // Pass 2: low byte of maxima within bin T1
#pragma unroll
    for (int q = 0; q < 4; ++q) hist4[q][t] = 0;
    __syncthreads();
    if (tmax && (tmax >> 8) == T1) atomicAdd(&hist4[w][tmax & 255u], 1u);
    __syncthreads();
    if (w == 0) {
        unsigned need = (unsigned)k_out - above1;
        int base = lane * 4;
        unsigned h[4];
#pragma unroll
        for (int r = 0; r < 4; ++r)
            h[r] = hist4[0][base + r] + hist4[1][base + r] +
                   hist4[2][base + r] + hist4[3][base + r];
        unsigned lsum = h[0] + h[1] + h[2] + h[3];
        unsigned suf = lsum;
#pragma unroll
        for (int off = 1; off < 64; off <<= 1) {
            unsigned o = __shfl_down(suf, off, 64);
            suf += (lane + off < 64) ? o : 0u;
        }
        unsigned Sr[5];
        Sr[4] = suf - lsum;
#pragma unroll
        for (int r = 3; r >= 0; --r) Sr[r] = Sr[r + 1] + h[r];
#pragma unroll
        for (int r = 0; r < 4; ++r)
            if (Sr[r] >= need && Sr[r + 1] < need)
                sT2 = (unsigned)(base + r);
    }
    __syncthreads();
    const unsigned Lt = (T1 << 8) | sT2;   // k-th largest thread-max (or 0)

    // Compact all row values >= Lt
#pragma unroll
    for (int s = 0; s < 32; ++s) {
        unsigned m = m16[s];
        if (m && m >= Lt) {
            unsigned idx = atomicAdd(&cand_cnt, 1u);
            if (idx < CAND_CAP) {
                int j = (s >> 3) * 2048 + t * 8 + (s & 7);
                cand[idx] = (m << 13) | (unsigned)(8191 - j);
            }
        }
    }
    __syncthreads();

    // Rank-by-counting extraction (keys unique -> ranks unique)
    const int m = (cand_cnt < CAND_CAP) ? (int)cand_cnt : CAND_CAP;
    const int reals = (k_out < nval) ? k_out : nval;
    for (int c = t; c < m; c += 256) {
        unsigned key = cand[c];
        int rank = 0;
        for (int x = 0; x < m; ++x) rank += (cand[x] > key) ? 1 : 0;
        if (rank < reals) {
            out_s[(size_t)i * k_out + rank] = scrub(inv_mono16(key >> 13));
            out_i[(size_t)i * k_out + rank] = (float)(8191 - (int)(key & 0x1FFFu));
        }
    }
    for (int r = reals + t; r < k_out; r += 256) {
        out_s[(size_t)i * k_out + r] = -1.0e30f;
        out_i[(size_t)i * k_out + r] = (float)r;
    }
}

extern "C" void kernel_launch(void* const* d_in, const int* in_sizes, int n_in,
                              void* d_out, int out_size, void* d_ws, size_t ws_size,
                              hipStream_t stream)
{
    const float* mentions = (const float*)d_in[0];   // [N x F]
    const float* W        = (const float*)d_in[1];   // [F x F]
    const float* bias     = (const float*)d_in[2];   // [F]

    const int F = in_sizes[2] > 0 ? in_sizes[2] : 1;
    const int N = in_sizes[0] / F;
    const int k_out = (N > 0) ? out_size / (2 * N) : 0;

    float* out_s = (float*)d_out;
    float* out_i = out_s + (size_t)N * k_out;

    prefill_kernel<<<256, 256, 0, stream>>>((float*)d_out, out_size);
    if (N <= 0 || k_out <= 0 || N > MAXN) return;

    dim3 blk(256);
    const bool tile_ok = (N % 128 == 0) && (F % 128 == 0);

    if (tile_ok) {
        // ws layout (bf16): Mb | Wb | Pb | sbuf
        ushort_t* Mb = (ushort_t*)d_ws;                    // N*F
        ushort_t* Wb = Mb + (size_t)N * F;                 // F*F
        ushort_t* Pb = Wb + (size_t)F * F;                 // N*F
        size_t fixed = ((size_t)2 * N * F + (size_t)F * F) * sizeof(ushort_t);
        size_t off = (fixed + 255) & ~(size_t)255;
        ushort_t* sbuf = (ushort_t*)((char*)d_ws + off);

        int chunk = (N < CHUNK_CAP) ? N : CHUNK_CAP;
        while (chunk > 128 && off + (size_t)chunk * N * sizeof(ushort_t) > ws_size)
            chunk >>= 1;

        if (off + (size_t)chunk * N * sizeof(ushort_t) <= ws_size) {
            cast_bf16_kernel<<<(N * F / 8 + 255) / 256, blk, 0, stream>>>(
                mentions, Mb, N * F);
            cast_bf16_kernel<<<(F * F / 8 + 255) / 256, blk, 0, stream>>>(
                W, Wb, F * F);

            // GEMM1: Pb = bf16(mentions @ W^T + b)   [N x F]  (2D grid, tri=0)
            gemm_bf16_nt<<<dim3(F / 128, N / 128), blk, 0, stream>>>(
                Mb, Wb, bias, Pb, F, F, 0, 0);

            // GEMM2 (packed triangular grid, ideally ONE dispatch) + top-k
            for (int r0 = 0; r0 < N; r0 += chunk) {
                int rows = (N - r0 < chunk) ? (N - r0) : chunk;
                int nby = rows / 128, base = r0 / 128;
                int T = nby * base + nby * (nby + 1) / 2;   // live tiles only
                gemm_bf16_nt<<<dim3(T, 1), blk, 0, stream>>>(
                    Pb + (size_t)r0 * F, Mb, nullptr, sbuf, F, N, base, 1);
                topk_kernel<<<rows, blk, 0, stream>>>(sbuf, N, r0, k_out, out_s, out_i);
            }
            return;
        }
    }

    // ---- fallback: naive f32 GEMMs + f32->bf16 cast of the score chunk ----
    {
        float* projf = (float*)d_ws;                           // N*F f32
        size_t o1 = (((size_t)N * F * sizeof(float)) + 255) & ~(size_t)255;
        float* sf = (float*)((char*)d_ws + o1);                // chunk*N f32
        int chunk = ((N + 127) / 128) * 128;
        while (chunk > 128 &&
               o1 + (size_t)chunk * N * (sizeof(float) + sizeof(ushort_t)) > ws_size)
            chunk >>= 1;
        size_t o2 = o1 + (((size_t)chunk * N * sizeof(float) + 255) & ~(size_t)255);
        ushort_t* sb = (ushort_t*)((char*)d_ws + o2);          // chunk*N bf16

        gemm_nt_naive<<<dim3((F + 15) / 16, (N + 15) / 16), blk, 0, stream>>>(
            mentions, W, bias, projf, F, F, N, F);
        for (int r0 = 0; r0 < N; r0 += chunk) {
            int rows = (N - r0 < chunk) ? (N - r0) : chunk;
            gemm_nt_naive<<<dim3((r0 + rows + 15) / 16, (rows + 15) / 16), blk, 0, stream>>>(
                projf + (size_t)r0 * F, mentions, nullptr, sf, F, N, rows, r0 + rows);
            cast_bf16_n_kernel<<<1024, blk, 0, stream>>>(sf, sb, (size_t)rows * N);
            topk_kernel<<<rows, blk, 0, stream>>>(sb, N, r0, k_out, out_s, out_i);
        }
    }
}